// Round 7
// baseline (486.772 us; speedup 1.0000x reference)
//
#include <hip/hip_runtime.h>
#include <hip/hip_bf16.h>

// NeighborAttention on MI355X. fp32 in/out, int32 mask.
// KEY INSIGHT (R0): query = broadcast of masked neighbor-mean -> all seq
// positions share one query per (b,h). Attention collapses to GEMV-scale work.
// R6: launch-overhead attack. R2-R5 data fits ~13us per kernel launch; kernel
// arithmetic sum is only ~40us. So: 10 launches -> 2. k_prep (zero barrier
// slots + neighbor pool) + ONE persistent mega-kernel (512 blocks x 256thr,
// __launch_bounds__(256,2) + 38KB LDS => >=2 blocks/CU capacity => all 512
// co-resident => manual device-scope barrier is deadlock-free). Stage bodies
// are R4's proven kernels mapped onto virtual block ids. Barrier: release
// atomicAdd on LLC counter + RELAXED agent polling + acquire fence on exit;
// slots zeroed by k_prep every call (graph-replay safe, no static state).

#define DIM  1024
#define NH   16
#define HD   64
#define BS   8
#define SEQ  1024
#define NNB  50
#define NBLK 512u

// workspace offsets (floats); all 16B-aligned
#define OF_XN    16
#define OF_Q     8208
#define OF_P     16400
#define OF_SCP   147472
#define OF_XWP   671760
#define OF_XW    2768912
#define OF_CTX   2899984
#define OF_OUTR  2908176   // total ~11.7 MB of ~256 MB ws

// ---------------- K1: zero barrier slots + masked neighbor mean pool ----------
__global__ void k_prep(const float* __restrict__ xnb, const float* __restrict__ nm,
                       float* __restrict__ ws){
  int b = blockIdx.x;
  if (b == 0 && threadIdx.x < 16) ((unsigned*)ws)[threadIdx.x] = 0u;
  float* xn = ws + OF_XN;
  int d = threadIdx.x*4;
  float4 acc = {0,0,0,0}; float wsum = 0.f;
  #pragma unroll 10
  for (int n=0; n<NNB; n++){
    float w = nm[b*NNB + n];
    float4 v = *(const float4*)(xnb + (size_t)(b*NNB + n)*DIM + d);
    acc.x += w*v.x; acc.y += w*v.y; acc.z += w*v.z; acc.w += w*v.w;
    wsum += w;
  }
  float inv = 1.f/wsum;
  acc.x*=inv; acc.y*=inv; acc.z*=inv; acc.w*=inv;
  *(float4*)(xn + b*DIM + d) = acc;
}

// device-wide barrier: all NBLK blocks resident by construction
__device__ __forceinline__ void gsync(unsigned* cnt, int slot){
  __syncthreads();
  if (threadIdx.x == 0){
    // release: flush this block's prior global writes, then signal arrival
    __hip_atomic_fetch_add(cnt + slot, 1u, __ATOMIC_RELEASE, __HIP_MEMORY_SCOPE_AGENT);
    // poll at LLC without per-iteration cache invalidation
    while (__hip_atomic_load(cnt + slot, __ATOMIC_RELAXED, __HIP_MEMORY_SCOPE_AGENT) < NBLK){
      __builtin_amdgcn_s_sleep(2);
    }
    __threadfence();   // acquire: invalidate stale L1/L2 before consuming peers' writes
  }
  __syncthreads();
}

// ---------------- K2: everything else, one persistent kernel ----------------
__global__ void __launch_bounds__(256, 2)
k_mega(const float* __restrict__ x, const int* __restrict__ mask,
       const float* __restrict__ qw, const float* __restrict__ qb,
       const float* __restrict__ kw,
       const float* __restrict__ vw, const float* __restrict__ vbias,
       const float* __restrict__ ow, const float* __restrict__ obias,
       const float* __restrict__ lng, const float* __restrict__ lnb,
       float* __restrict__ ws, float* __restrict__ out)
{
  unsigned* cnt = (unsigned*)ws;
  float* xn   = ws + OF_XN;
  float* q    = ws + OF_Q;
  float* p    = ws + OF_P;
  float* scp  = ws + OF_SCP;   // 4 kc-slabs; slab0 becomes weights
  float* xwp  = ws + OF_XWP;   // 16 s-chunk slabs
  float* xw   = ws + OF_XW;
  float* ctx  = ws + OF_CTX;
  float* outr = ws + OF_OUTR;

  __shared__ __align__(16) unsigned char smem[38912];
  int vb  = blockIdx.x;
  int tid = threadIdx.x;
  int wv  = tid >> 6, ln = tid & 63;

  // ---- stage 1: q[b,j] = (xn.qw[j,:]+qb)/8 (256 active blocks) ----
  if (vb < 256){
    int j = vb*4 + wv;
    float acc[BS] = {0,0,0,0,0,0,0,0};
    #pragma unroll
    for (int i=0; i<4; i++){
      int d = ln*4 + 256*i;
      float4 wt = *(const float4*)(qw + (size_t)j*DIM + d);
      #pragma unroll
      for (int b=0; b<BS; b++){
        float4 xv = *(const float4*)(xn + b*DIM + d);
        acc[b] += wt.x*xv.x + wt.y*xv.y + wt.z*xv.z + wt.w*xv.w;
      }
    }
    #pragma unroll
    for (int off=32; off>=1; off>>=1){
      #pragma unroll
      for (int b=0; b<BS; b++) acc[b] += __shfl_down(acc[b], off, 64);
    }
    if (ln == 0){
      float bias = qb[j];
      #pragma unroll
      for (int b=0; b<BS; b++) q[b*DIM + j] = (acc[b] + bias) * 0.125f;
    }
  }
  gsync(cnt, 0);

  // ---- stage 2: p[b,h,d] = sum_j q[b,h64+j]*kw[h64+j,d] (512 blocks) ----
  {
    int dc = vb & 3, h = (vb >> 2) & 15, b = vb >> 6;
    int d = dc*256 + tid;
    const float* qrow = q + b*DIM + h*HD;
    float acc = 0.f;
    #pragma unroll 8
    for (int j=0; j<HD; j++)
      acc += qrow[j] * kw[(size_t)(h*HD + j)*DIM + d];
    p[(size_t)(b*NH + h)*DIM + d] = acc;
  }
  gsync(cnt, 1);

  // ---- stage 3: scores scp[kc][b,h,s] (512 blocks = 16 sc x 8 b x 4 kc) ----
  {
    int s0 = (vb & 15) * 64;
    int b  = (vb >> 4) & 7;
    int kc = vb >> 7;
    int kbase = kc * 256;
    float4* plds = (float4*)smem;               // [d][h/4], 20480 B
    float*  xlds = (float*)(smem + 20480);      // [s][68],  17408 B
    float* pf = (float*)plds;
    #pragma unroll
    for (int it=0; it<16; it++){
      int idx = it*256 + tid;
      int d = idx & 255, h = idx >> 8;
      pf[d*20 + h] = p[(size_t)(b*NH + h)*DIM + kbase + d];
    }
    int s = tid & 63, g = tid >> 6;
    float acc[4] = {0.f,0.f,0.f,0.f};
    for (int dk=0; dk<4; dk++){
      __syncthreads();
      #pragma unroll
      for (int it=0; it<4; it++){
        int idx = it*256 + tid;
        int dd4 = idx & 15, ss = idx >> 4;
        float4 v = *(const float4*)(x + (size_t)(b*SEQ + s0 + ss)*DIM + kbase + dk*64 + dd4*4);
        *(float4*)(xlds + ss*68 + dd4*4) = v;
      }
      __syncthreads();
      #pragma unroll 4
      for (int dd4=0; dd4<16; dd4++){
        float4 xq = *(const float4*)(xlds + s*68 + dd4*4);
        int dbase = (dk*64 + dd4*4)*5 + g;
        float4 p0 = plds[dbase], p1 = plds[dbase+5], p2 = plds[dbase+10], p3 = plds[dbase+15];
        acc[0] += xq.x*p0.x + xq.y*p1.x + xq.z*p2.x + xq.w*p3.x;
        acc[1] += xq.x*p0.y + xq.y*p1.y + xq.z*p2.y + xq.w*p3.y;
        acc[2] += xq.x*p0.z + xq.y*p1.z + xq.z*p2.z + xq.w*p3.z;
        acc[3] += xq.x*p0.w + xq.y*p1.w + xq.z*p2.w + xq.w*p3.w;
      }
    }
    float* slab = scp + (size_t)kc*(BS*NH*SEQ);
    #pragma unroll
    for (int u=0; u<4; u++)
      slab[(size_t)(b*NH + g*4 + u)*SEQ + s0 + s] = acc[u];
  }
  gsync(cnt, 2);

  // ---- stage 4: softmax (sums 4 slabs, weights -> slab0; 128 active) ----
  if (vb < 128){
    int b = vb >> 4, h = vb & 15;
    size_t rowoff = (size_t)(b*NH + h)*SEQ;
    float* r1 = (float*)smem;
    float* r2 = r1 + 4;
    float v[4];
    float mx = -3e38f;
    #pragma unroll
    for (int i=0; i<4; i++){
      int s = tid + 256*i;
      float v0 = 0.f;
      #pragma unroll
      for (int kc=0; kc<4; kc++) v0 += scp[(size_t)kc*(BS*NH*SEQ) + rowoff + s];
      if (mask[b*SEQ + s] == 0) v0 = -1e30f;
      v[i] = v0;
      mx = fmaxf(mx, v0);
    }
    #pragma unroll
    for (int off=32; off>=1; off>>=1) mx = fmaxf(mx, __shfl_xor(mx, off, 64));
    if (ln == 0) r1[wv] = mx;
    __syncthreads();
    mx = fmaxf(fmaxf(r1[0], r1[1]), fmaxf(r1[2], r1[3]));
    float sum = 0.f;
    #pragma unroll
    for (int i=0; i<4; i++){ v[i] = __expf(v[i] - mx); sum += v[i]; }
    #pragma unroll
    for (int off=32; off>=1; off>>=1) sum += __shfl_xor(sum, off, 64);
    if (ln == 0) r2[wv] = sum;
    __syncthreads();
    sum = r2[0] + r2[1] + r2[2] + r2[3];
    float inv = 1.f / sum;
    #pragma unroll
    for (int i=0; i<4; i++) scp[rowoff + tid + 256*i] = v[i] * inv;
  }
  gsync(cnt, 3);

  // ---- stage 5: wpool partials (512 blocks = 4 dc x 8 b x 16 scn) ----
  {
    int dc = vb & 3, b = (vb >> 2) & 7, scn = vb >> 5;
    float4* wlds = (float4*)smem;               // [s][h/4], 5120 B
    float* wf = (float*)wlds;
    #pragma unroll
    for (int it=0; it<4; it++){
      int idx = it*256 + tid;
      int ss = idx >> 4, hh = idx & 15;
      wf[ss*20 + hh] = scp[(size_t)(b*NH + hh)*SEQ + scn*64 + ss];
    }
    __syncthreads();
    int d = dc*256 + ln*4;
    const float* xbase = x + (size_t)(b*SEQ + scn*64)*DIM + d;
    float4 a0={0,0,0,0}, a1={0,0,0,0}, a2={0,0,0,0}, a3={0,0,0,0};
    for (int sb=0; sb<64; sb+=8){
      float4 xq[8];
      #pragma unroll
      for (int u=0; u<8; u++)
        xq[u] = *(const float4*)(xbase + (size_t)(sb+u)*DIM);
      #pragma unroll
      for (int u=0; u<8; u++){
        float4 wq = wlds[(sb+u)*5 + wv];
        a0.x+=xq[u].x*wq.x; a0.y+=xq[u].y*wq.x; a0.z+=xq[u].z*wq.x; a0.w+=xq[u].w*wq.x;
        a1.x+=xq[u].x*wq.y; a1.y+=xq[u].y*wq.y; a1.z+=xq[u].z*wq.y; a1.w+=xq[u].w*wq.y;
        a2.x+=xq[u].x*wq.z; a2.y+=xq[u].y*wq.z; a2.z+=xq[u].z*wq.z; a2.w+=xq[u].w*wq.z;
        a3.x+=xq[u].x*wq.w; a3.y+=xq[u].y*wq.w; a3.z+=xq[u].z*wq.w; a3.w+=xq[u].w*wq.w;
      }
    }
    float* dst = xwp + (size_t)scn*(BS*NH*DIM) + (size_t)(b*NH + wv*4)*DIM + d;
    *(float4*)(dst                 ) = a0;
    *(float4*)(dst +   (size_t)DIM ) = a1;
    *(float4*)(dst + 2*(size_t)DIM ) = a2;
    *(float4*)(dst + 3*(size_t)DIM ) = a3;
  }
  gsync(cnt, 4);

  // ---- stage 6: xw = sum of 16 slabs (512 blocks, 1 elem/thread) ----
  {
    int id = vb*256 + tid;
    float v = 0.f;
    #pragma unroll
    for (int scn=0; scn<16; scn++) v += xwp[(size_t)scn*(BS*NH*DIM) + id];
    xw[id] = v;
  }
  gsync(cnt, 5);

  // ---- stage 7: ctx[b,jo] = xw[b,h,:].vw[jo,:] + vb[jo] (256 active) ----
  if (vb < 256){
    int jo = vb*4 + wv;
    int h  = jo >> 6;
    float acc[BS] = {0,0,0,0,0,0,0,0};
    #pragma unroll
    for (int i=0; i<4; i++){
      int d = ln*4 + 256*i;
      float4 vv = *(const float4*)(vw + (size_t)jo*DIM + d);
      #pragma unroll
      for (int b=0; b<BS; b++){
        float4 xv = *(const float4*)(xw + (size_t)(b*NH + h)*DIM + d);
        acc[b] += vv.x*xv.x + vv.y*xv.y + vv.z*xv.z + vv.w*xv.w;
      }
    }
    #pragma unroll
    for (int off=32; off>=1; off>>=1){
      #pragma unroll
      for (int b=0; b<BS; b++) acc[b] += __shfl_down(acc[b], off, 64);
    }
    if (ln == 0){
      float bias = vbias[jo];
      #pragma unroll
      for (int b=0; b<BS; b++) ctx[b*DIM + jo] = acc[b] + bias;
    }
  }
  gsync(cnt, 6);

  // ---- stage 8: outr[b,i] = ctx[b,:].ow[i,:] + ob[i] (256 active) ----
  if (vb < 256){
    int io = vb*4 + wv;
    float acc[BS] = {0,0,0,0,0,0,0,0};
    #pragma unroll
    for (int i=0; i<4; i++){
      int d = ln*4 + 256*i;
      float4 wt = *(const float4*)(ow + (size_t)io*DIM + d);
      #pragma unroll
      for (int b=0; b<BS; b++){
        float4 cv = *(const float4*)(ctx + b*DIM + d);
        acc[b] += wt.x*cv.x + wt.y*cv.y + wt.z*cv.z + wt.w*cv.w;
      }
    }
    #pragma unroll
    for (int off=32; off>=1; off>>=1){
      #pragma unroll
      for (int b=0; b<BS; b++) acc[b] += __shfl_down(acc[b], off, 64);
    }
    if (ln == 0){
      float bias = obias[io];
      #pragma unroll
      for (int b=0; b<BS; b++) outr[b*DIM + io] = acc[b] + bias;
    }
  }
  gsync(cnt, 7);

  // ---- stage 9: LayerNorm, 16 rows per block ----
  {
    float* r1 = (float*)smem;
    float* r2 = r1 + 4;
    for (int r=0; r<16; r++){
      int row = vb*16 + r;
      int b = row >> 10;
      size_t base = (size_t)row * DIM;
      float4 xv = ((const float4*)(x + base))[tid];
      float4 ov = ((const float4*)(outr + (size_t)b*DIM))[tid];
      float4 h;
      h.x = xv.x + ov.x; h.y = xv.y + ov.y; h.z = xv.z + ov.z; h.w = xv.w + ov.w;
      float s  = h.x + h.y + h.z + h.w;
      float s2 = h.x*h.x + h.y*h.y + h.z*h.z + h.w*h.w;
      #pragma unroll
      for (int off=32; off>=1; off>>=1){
        s  += __shfl_xor(s,  off, 64);
        s2 += __shfl_xor(s2, off, 64);
      }
      if (ln == 0){ r1[wv] = s; r2[wv] = s2; }
      __syncthreads();
      s  = r1[0] + r1[1] + r1[2] + r1[3];
      s2 = r2[0] + r2[1] + r2[2] + r2[3];
      float mu   = s  * (1.f/1024.f);
      float var  = s2 * (1.f/1024.f) - mu*mu;
      float rstd = rsqrtf(var + 1e-12f);
      float4 gv = ((const float4*)lng)[tid];
      float4 bv = ((const float4*)lnb)[tid];
      float4 y;
      y.x = (h.x - mu)*rstd*gv.x + bv.x;
      y.y = (h.y - mu)*rstd*gv.y + bv.y;
      y.z = (h.z - mu)*rstd*gv.z + bv.z;
      y.w = (h.w - mu)*rstd*gv.w + bv.w;
      ((float4*)(out + base))[tid] = y;
      __syncthreads();   // r1/r2 reused next row
    }
  }
}

extern "C" void kernel_launch(void* const* d_in, const int* in_sizes, int n_in,
                              void* d_out, int out_size, void* d_ws, size_t ws_size,
                              hipStream_t stream) {
  const float* x    = (const float*)d_in[0];
  const float* xnb  = (const float*)d_in[1];
  const int*   mask = (const int*  )d_in[2];
  const float* nm   = (const float*)d_in[3];
  const float* qw   = (const float*)d_in[4];
  const float* qb   = (const float*)d_in[5];
  const float* kw   = (const float*)d_in[6];
  // d_in[7] = kb: softmax-invariant constant, unused
  const float* vw   = (const float*)d_in[8];
  const float* vb   = (const float*)d_in[9];
  const float* ow   = (const float*)d_in[10];
  const float* ob   = (const float*)d_in[11];
  const float* lng  = (const float*)d_in[12];
  const float* lnb  = (const float*)d_in[13];
  float* out = (float*)d_out;
  float* ws  = (float*)d_ws;

  k_prep <<<BS,   256, 0, stream>>>(xnb, nm, ws);
  k_mega <<<NBLK, 256, 0, stream>>>(x, mask, qw, qb, kw, vw, vb, ow, ob,
                                    lng, lnb, ws, out);
}

// Round 8
// 465.555 us; speedup vs baseline: 1.0456x; 1.0456x over previous
//
#include <hip/hip_runtime.h>
#include <hip/hip_bf16.h>

// NeighborAttention on MI355X. fp32 in/out, int32 mask.
// KEY INSIGHT (R0): query = broadcast of masked neighbor-mean -> all seq
// positions share one query per (b,h). Attention collapses to GEMV-scale work.
// R6 POST-MORTEM: mega-kernel barriers cost 41us each because the RELAXED
// agent-scope polling LOAD is served by the non-cross-XCD-coherent L2 -> the
// counter line goes stale until eviction. VALUBusy 3% proved 330us of spin.
// R7: poll with RMW fetch_add(0) instead (RMWs execute at LLC = coherence
// point, always fresh) + s_sleep(32) backoff. Also: pool+q+p fused into one
// stage (xnb/qw/kw are LLC-hot; 128 blocks recompute xn redundantly), barrier
// count 8->7, k_prep replaced by a 64B hipMemsetAsync. 2 dispatches total.
// Fallback if k_mega still ~300us: revert to R4 multi-kernel (171us).

#define DIM  1024
#define NH   16
#define HD   64
#define BS   8
#define SEQ  1024
#define NNB  50
#define NBLK 512u

// workspace offsets (floats); all 16B-aligned. slot 0..15 = barrier counters.
#define OF_P     16400
#define OF_SCP   147472
#define OF_XWP   671760
#define OF_XW    2768912
#define OF_CTX   2899984
#define OF_OUTR  2908176   // total ~11.7 MB of ~256 MB ws

// device-wide barrier: all NBLK blocks resident by construction.
// Arrival: release RMW (flushes prior writes for agent visibility).
// Poll: RMW add-0 — executes at LLC, immune to stale per-XCD L2 (R6 bug).
__device__ __forceinline__ void gsync(unsigned* cnt, int slot){
  __syncthreads();
  if (threadIdx.x == 0){
    __hip_atomic_fetch_add(cnt + slot, 1u, __ATOMIC_RELEASE, __HIP_MEMORY_SCOPE_AGENT);
    while (__hip_atomic_fetch_add(cnt + slot, 0u, __ATOMIC_RELAXED,
                                  __HIP_MEMORY_SCOPE_AGENT) < NBLK){
      __builtin_amdgcn_s_sleep(32);   // ~0.85us backoff: 512 pollers stay under LLC atomic rate
    }
    __threadfence();   // acquire: invalidate stale caches before consuming peers' writes
  }
  __syncthreads();
}

__global__ void __launch_bounds__(256, 2)
k_mega(const float* __restrict__ x, const float* __restrict__ xnb,
       const int* __restrict__ mask, const float* __restrict__ nm,
       const float* __restrict__ qw, const float* __restrict__ qb,
       const float* __restrict__ kw,
       const float* __restrict__ vw, const float* __restrict__ vbias,
       const float* __restrict__ ow, const float* __restrict__ obias,
       const float* __restrict__ lng, const float* __restrict__ lnb,
       float* __restrict__ ws, float* __restrict__ out)
{
  unsigned* cnt = (unsigned*)ws;
  float* p    = ws + OF_P;
  float* scp  = ws + OF_SCP;   // 4 kc-slabs; slab0 becomes weights
  float* xwp  = ws + OF_XWP;   // 16 s-chunk slabs
  float* xw   = ws + OF_XW;
  float* ctx  = ws + OF_CTX;
  float* outr = ws + OF_OUTR;

  __shared__ __align__(16) unsigned char smem[38912];
  int vb  = blockIdx.x;
  int tid = threadIdx.x;
  int wv  = tid >> 6, ln = tid & 63;

  // ---- stage A: fused neighbor-pool + q + p, per (h,b); 128 active blocks ----
  if (vb < 128){
    int h = vb & 15, b = vb >> 4;
    float* xnl = (float*)smem;          // 1024 f
    float* qp  = xnl + 1024;            // 256 f
    float* ql  = qp + 256;              // 64 f
    {
      int d = tid*4;
      float4 acc = {0,0,0,0}; float wsum = 0.f;
      #pragma unroll 10
      for (int n=0; n<NNB; n++){
        float w = nm[b*NNB + n];
        float4 v = *(const float4*)(xnb + (size_t)(b*NNB + n)*DIM + d);
        acc.x += w*v.x; acc.y += w*v.y; acc.z += w*v.z; acc.w += w*v.w;
        wsum += w;
      }
      float inv = 1.f/wsum;
      acc.x*=inv; acc.y*=inv; acc.z*=inv; acc.w*=inv;
      *(float4*)(xnl + d) = acc;
    }
    __syncthreads();
    {  // q partial: lane ln -> row h*64+ln, wave wv -> 256-d chunk
      const float* qrow = qw + (size_t)(h*HD + ln)*DIM + wv*256;
      const float* xrow = xnl + wv*256;
      float part = 0.f;
      #pragma unroll 16
      for (int i=0; i<64; i++){
        float4 a = *(const float4*)(qrow + i*4);
        float4 c = *(const float4*)(xrow + i*4);
        part += a.x*c.x + a.y*c.y + a.z*c.z + a.w*c.w;
      }
      qp[wv*64 + ln] = part;
    }
    __syncthreads();
    if (wv == 0){
      float qv = qp[ln] + qp[64+ln] + qp[128+ln] + qp[192+ln];
      ql[ln] = (qv + qb[h*HD + ln]) * 0.125f;
    }
    __syncthreads();
    {  // p[b,h,d] = sum_j ql[j]*kw[h*64+j,d]
      int d = tid*4;
      float4 acc = {0,0,0,0};
      #pragma unroll 8
      for (int j=0; j<HD; j++){
        float qj = ql[j];
        float4 kv = *(const float4*)(kw + (size_t)(h*HD + j)*DIM + d);
        acc.x += qj*kv.x; acc.y += qj*kv.y; acc.z += qj*kv.z; acc.w += qj*kv.w;
      }
      *(float4*)(p + (size_t)(b*NH + h)*DIM + d) = acc;
    }
  }
  gsync(cnt, 0);

  // ---- stage B: scores scp[kc][b,h,s] (512 blocks = 16 sc x 8 b x 4 kc) ----
  {
    int s0 = (vb & 15) * 64;
    int b  = (vb >> 4) & 7;
    int kc = vb >> 7;
    int kbase = kc * 256;
    float4* plds = (float4*)smem;               // [d][h/4], 20480 B
    float*  xlds = (float*)(smem + 20480);      // [s][68],  17408 B
    float* pf = (float*)plds;
    #pragma unroll
    for (int it=0; it<16; it++){
      int idx = it*256 + tid;
      int d = idx & 255, h = idx >> 8;
      pf[d*20 + h] = p[(size_t)(b*NH + h)*DIM + kbase + d];
    }
    int s = tid & 63, g = tid >> 6;
    float acc[4] = {0.f,0.f,0.f,0.f};
    for (int dk=0; dk<4; dk++){
      __syncthreads();
      #pragma unroll
      for (int it=0; it<4; it++){
        int idx = it*256 + tid;
        int dd4 = idx & 15, ss = idx >> 4;
        float4 v = *(const float4*)(x + (size_t)(b*SEQ + s0 + ss)*DIM + kbase + dk*64 + dd4*4);
        *(float4*)(xlds + ss*68 + dd4*4) = v;
      }
      __syncthreads();
      #pragma unroll 4
      for (int dd4=0; dd4<16; dd4++){
        float4 xq = *(const float4*)(xlds + s*68 + dd4*4);
        int dbase = (dk*64 + dd4*4)*5 + g;
        float4 p0 = plds[dbase], p1 = plds[dbase+5], p2 = plds[dbase+10], p3 = plds[dbase+15];
        acc[0] += xq.x*p0.x + xq.y*p1.x + xq.z*p2.x + xq.w*p3.x;
        acc[1] += xq.x*p0.y + xq.y*p1.y + xq.z*p2.y + xq.w*p3.y;
        acc[2] += xq.x*p0.z + xq.y*p1.z + xq.z*p2.z + xq.w*p3.z;
        acc[3] += xq.x*p0.w + xq.y*p1.w + xq.z*p2.w + xq.w*p3.w;
      }
    }
    float* slab = scp + (size_t)kc*(BS*NH*SEQ);
    #pragma unroll
    for (int u=0; u<4; u++)
      slab[(size_t)(b*NH + g*4 + u)*SEQ + s0 + s] = acc[u];
  }
  gsync(cnt, 1);

  // ---- stage C: softmax (sums 4 slabs, weights -> slab0; 128 active) ----
  if (vb < 128){
    int b = vb >> 4, h = vb & 15;
    size_t rowoff = (size_t)(b*NH + h)*SEQ;
    float* r1 = (float*)smem;
    float* r2 = r1 + 4;
    float v[4];
    float mx = -3e38f;
    #pragma unroll
    for (int i=0; i<4; i++){
      int s = tid + 256*i;
      float v0 = 0.f;
      #pragma unroll
      for (int kc=0; kc<4; kc++) v0 += scp[(size_t)kc*(BS*NH*SEQ) + rowoff + s];
      if (mask[b*SEQ + s] == 0) v0 = -1e30f;
      v[i] = v0;
      mx = fmaxf(mx, v0);
    }
    #pragma unroll
    for (int off=32; off>=1; off>>=1) mx = fmaxf(mx, __shfl_xor(mx, off, 64));
    if (ln == 0) r1[wv] = mx;
    __syncthreads();
    mx = fmaxf(fmaxf(r1[0], r1[1]), fmaxf(r1[2], r1[3]));
    float sum = 0.f;
    #pragma unroll
    for (int i=0; i<4; i++){ v[i] = __expf(v[i] - mx); sum += v[i]; }
    #pragma unroll
    for (int off=32; off>=1; off>>=1) sum += __shfl_xor(sum, off, 64);
    if (ln == 0) r2[wv] = sum;
    __syncthreads();
    sum = r2[0] + r2[1] + r2[2] + r2[3];
    float inv = 1.f / sum;
    #pragma unroll
    for (int i=0; i<4; i++) scp[rowoff + tid + 256*i] = v[i] * inv;
  }
  gsync(cnt, 2);

  // ---- stage D: wpool partials (512 blocks = 4 dc x 8 b x 16 scn) ----
  {
    int dc = vb & 3, b = (vb >> 2) & 7, scn = vb >> 5;
    float4* wlds = (float4*)smem;               // [s][h/4], 5120 B
    float* wf = (float*)wlds;
    #pragma unroll
    for (int it=0; it<4; it++){
      int idx = it*256 + tid;
      int ss = idx >> 4, hh = idx & 15;
      wf[ss*20 + hh] = scp[(size_t)(b*NH + hh)*SEQ + scn*64 + ss];
    }
    __syncthreads();
    int d = dc*256 + ln*4;
    const float* xbase = x + (size_t)(b*SEQ + scn*64)*DIM + d;
    float4 a0={0,0,0,0}, a1={0,0,0,0}, a2={0,0,0,0}, a3={0,0,0,0};
    for (int sb=0; sb<64; sb+=8){
      float4 xq[8];
      #pragma unroll
      for (int u=0; u<8; u++)
        xq[u] = *(const float4*)(xbase + (size_t)(sb+u)*DIM);
      #pragma unroll
      for (int u=0; u<8; u++){
        float4 wq = wlds[(sb+u)*5 + wv];
        a0.x+=xq[u].x*wq.x; a0.y+=xq[u].y*wq.x; a0.z+=xq[u].z*wq.x; a0.w+=xq[u].w*wq.x;
        a1.x+=xq[u].x*wq.y; a1.y+=xq[u].y*wq.y; a1.z+=xq[u].z*wq.y; a1.w+=xq[u].w*wq.y;
        a2.x+=xq[u].x*wq.z; a2.y+=xq[u].y*wq.z; a2.z+=xq[u].z*wq.z; a2.w+=xq[u].w*wq.z;
        a3.x+=xq[u].x*wq.w; a3.y+=xq[u].y*wq.w; a3.z+=xq[u].z*wq.w; a3.w+=xq[u].w*wq.w;
      }
    }
    float* dst = xwp + (size_t)scn*(BS*NH*DIM) + (size_t)(b*NH + wv*4)*DIM + d;
    *(float4*)(dst                 ) = a0;
    *(float4*)(dst +   (size_t)DIM ) = a1;
    *(float4*)(dst + 2*(size_t)DIM ) = a2;
    *(float4*)(dst + 3*(size_t)DIM ) = a3;
  }
  gsync(cnt, 3);

  // ---- stage E: xw = sum of 16 slabs (512 blocks, 1 elem/thread) ----
  {
    int id = vb*256 + tid;
    float v = 0.f;
    #pragma unroll
    for (int scn=0; scn<16; scn++) v += xwp[(size_t)scn*(BS*NH*DIM) + id];
    xw[id] = v;
  }
  gsync(cnt, 4);

  // ---- stage F: ctx[b,jo] = xw[b,h,:].vw[jo,:] + vb[jo] (256 active) ----
  if (vb < 256){
    int jo = vb*4 + wv;
    int h  = jo >> 6;
    float acc[BS] = {0,0,0,0,0,0,0,0};
    #pragma unroll
    for (int i=0; i<4; i++){
      int d = ln*4 + 256*i;
      float4 vv = *(const float4*)(vw + (size_t)jo*DIM + d);
      #pragma unroll
      for (int b=0; b<BS; b++){
        float4 xv = *(const float4*)(xw + (size_t)(b*NH + h)*DIM + d);
        acc[b] += vv.x*xv.x + vv.y*xv.y + vv.z*xv.z + vv.w*xv.w;
      }
    }
    #pragma unroll
    for (int off=32; off>=1; off>>=1){
      #pragma unroll
      for (int b=0; b<BS; b++) acc[b] += __shfl_down(acc[b], off, 64);
    }
    if (ln == 0){
      float bias = vbias[jo];
      #pragma unroll
      for (int b=0; b<BS; b++) ctx[b*DIM + jo] = acc[b] + bias;
    }
  }
  gsync(cnt, 5);

  // ---- stage G: outr[b,i] = ctx[b,:].ow[i,:] + ob[i] (256 active) ----
  if (vb < 256){
    int io = vb*4 + wv;
    float acc[BS] = {0,0,0,0,0,0,0,0};
    #pragma unroll
    for (int i=0; i<4; i++){
      int d = ln*4 + 256*i;
      float4 wt = *(const float4*)(ow + (size_t)io*DIM + d);
      #pragma unroll
      for (int b=0; b<BS; b++){
        float4 cv = *(const float4*)(ctx + b*DIM + d);
        acc[b] += wt.x*cv.x + wt.y*cv.y + wt.z*cv.z + wt.w*cv.w;
      }
    }
    #pragma unroll
    for (int off=32; off>=1; off>>=1){
      #pragma unroll
      for (int b=0; b<BS; b++) acc[b] += __shfl_down(acc[b], off, 64);
    }
    if (ln == 0){
      float bias = obias[io];
      #pragma unroll
      for (int b=0; b<BS; b++) outr[b*DIM + io] = acc[b] + bias;
    }
  }
  gsync(cnt, 6);

  // ---- stage H: LayerNorm, 16 rows per block ----
  {
    float* r1 = (float*)smem;
    float* r2 = r1 + 4;
    for (int r=0; r<16; r++){
      int row = vb*16 + r;
      int b = row >> 10;
      size_t base = (size_t)row * DIM;
      float4 xv = ((const float4*)(x + base))[tid];
      float4 ov = ((const float4*)(outr + (size_t)b*DIM))[tid];
      float4 h;
      h.x = xv.x + ov.x; h.y = xv.y + ov.y; h.z = xv.z + ov.z; h.w = xv.w + ov.w;
      float s  = h.x + h.y + h.z + h.w;
      float s2 = h.x*h.x + h.y*h.y + h.z*h.z + h.w*h.w;
      #pragma unroll
      for (int off=32; off>=1; off>>=1){
        s  += __shfl_xor(s,  off, 64);
        s2 += __shfl_xor(s2, off, 64);
      }
      if (ln == 0){ r1[wv] = s; r2[wv] = s2; }
      __syncthreads();
      s  = r1[0] + r1[1] + r1[2] + r1[3];
      s2 = r2[0] + r2[1] + r2[2] + r2[3];
      float mu   = s  * (1.f/1024.f);
      float var  = s2 * (1.f/1024.f) - mu*mu;
      float rstd = rsqrtf(var + 1e-12f);
      float4 gv = ((const float4*)lng)[tid];
      float4 bv = ((const float4*)lnb)[tid];
      float4 y;
      y.x = (h.x - mu)*rstd*gv.x + bv.x;
      y.y = (h.y - mu)*rstd*gv.y + bv.y;
      y.z = (h.z - mu)*rstd*gv.z + bv.z;
      y.w = (h.w - mu)*rstd*gv.w + bv.w;
      ((float4*)(out + base))[tid] = y;
      __syncthreads();   // r1/r2 reused next row
    }
  }
}

extern "C" void kernel_launch(void* const* d_in, const int* in_sizes, int n_in,
                              void* d_out, int out_size, void* d_ws, size_t ws_size,
                              hipStream_t stream) {
  const float* x    = (const float*)d_in[0];
  const float* xnb  = (const float*)d_in[1];
  const int*   mask = (const int*  )d_in[2];
  const float* nm   = (const float*)d_in[3];
  const float* qw   = (const float*)d_in[4];
  const float* qb   = (const float*)d_in[5];
  const float* kw   = (const float*)d_in[6];
  // d_in[7] = kb: softmax-invariant constant, unused
  const float* vw   = (const float*)d_in[8];
  const float* vb   = (const float*)d_in[9];
  const float* ow   = (const float*)d_in[10];
  const float* ob   = (const float*)d_in[11];
  const float* lng  = (const float*)d_in[12];
  const float* lnb  = (const float*)d_in[13];
  float* out = (float*)d_out;
  float* ws  = (float*)d_ws;

  hipMemsetAsync(ws, 0, 16*sizeof(unsigned), stream);   // barrier counters
  k_mega <<<NBLK, 256, 0, stream>>>(x, xnb, mask, nm, qw, qb, kw, vw, vb,
                                    ow, ob, lng, lnb, ws, out);
}

// Round 9
// 168.287 us; speedup vs baseline: 2.8925x; 2.7664x over previous
//
#include <hip/hip_runtime.h>
#include <hip/hip_bf16.h>

// NeighborAttention on MI355X. fp32 in/out, int32 mask.
// KEY INSIGHT (R0): query = broadcast of masked neighbor-mean -> all seq
// positions share one query per (b,h). Attention collapses to GEMV-scale work.
// R6/R7 POST-MORTEM (recorded): device-wide software barriers cost ~40us EACH
// on MI355X regardless of poll mechanism (agent-scope release/acquire forces
// per-XCD L2 writeback/invalidate chip-wide). Mega-kernel abandoned; kernel
// boundaries are the cheap barrier (~5-10us).
// R8: R4's 171us multi-kernel, compressed 10 -> 7 launches:
//   - k_prep = pool+q+p fused (R7 stage A, proven in-situ)
//   - softmax kernel ELIMINATED: k_wpe computes e=exp(score)*mask on the fly
//     (R5 proved no-max-sub exp is safe), accumulates unnormalized num + den
//     partials; k_xwred divides. No atomics -> no memset.

#define DIM  1024
#define NH   16
#define HD   64
#define BS   8
#define SEQ  1024
#define NNB  50

// workspace offsets (floats), all 16B-aligned
#define OF_P     16
#define OF_SCP   131088
#define OF_NUMP  655376
#define OF_DENP  2752528
#define OF_XW    2754576
#define OF_CTX   2885648
#define OF_OUTR  2893840

// ---------------- K1: fused neighbor-pool + q + p, one block per (h,b) -------
__global__ void k_prep(const float* __restrict__ xnb, const float* __restrict__ nm,
                       const float* __restrict__ qw, const float* __restrict__ qb,
                       const float* __restrict__ kw, float* __restrict__ p){
  int h = blockIdx.x & 15, b = blockIdx.x >> 4;
  int tid = threadIdx.x, wv = tid >> 6, ln = tid & 63;
  __shared__ float xnl[1024];
  __shared__ float qp[256];
  __shared__ float ql[64];
  {  // masked neighbor mean
    int d = tid*4;
    float4 acc = {0,0,0,0}; float wsum = 0.f;
    #pragma unroll 10
    for (int n=0; n<NNB; n++){
      float w = nm[b*NNB + n];
      float4 v = *(const float4*)(xnb + (size_t)(b*NNB + n)*DIM + d);
      acc.x += w*v.x; acc.y += w*v.y; acc.z += w*v.z; acc.w += w*v.w;
      wsum += w;
    }
    float inv = 1.f/wsum;
    acc.x*=inv; acc.y*=inv; acc.z*=inv; acc.w*=inv;
    *(float4*)(xnl + d) = acc;
  }
  __syncthreads();
  {  // q partial: lane ln -> row h*64+ln of qw, wave wv -> 256-d chunk
    const float* qrow = qw + (size_t)(h*HD + ln)*DIM + wv*256;
    const float* xrow = xnl + wv*256;
    float part = 0.f;
    #pragma unroll 16
    for (int i=0; i<64; i++){
      float4 a = *(const float4*)(qrow + i*4);
      float4 c = *(const float4*)(xrow + i*4);
      part += a.x*c.x + a.y*c.y + a.z*c.z + a.w*c.w;
    }
    qp[wv*64 + ln] = part;
  }
  __syncthreads();
  if (wv == 0){
    float qv = qp[ln] + qp[64+ln] + qp[128+ln] + qp[192+ln];
    ql[ln] = (qv + qb[h*HD + ln]) * 0.125f;
  }
  __syncthreads();
  {  // p[b,h,d] = sum_j ql[j]*kw[h*64+j,d]
    int d = tid*4;
    float4 acc = {0,0,0,0};
    #pragma unroll 8
    for (int j=0; j<HD; j++){
      float qj = ql[j];
      float4 kv = *(const float4*)(kw + (size_t)(h*HD + j)*DIM + d);
      acc.x += qj*kv.x; acc.y += qj*kv.y; acc.z += qj*kv.z; acc.w += qj*kv.w;
    }
    *(float4*)(p + (size_t)(b*NH + h)*DIM + d) = acc;
  }
}

// ---------------- K2: scp[kc][b,h,s] = x[b,s,kc-chunk].p[b,h,kc-chunk] -------
// grid (16 sc, 8 b, 4 kc), block 256 = 4 waves; wave g -> heads g*4..+3.
__global__ void k_scores(const float* __restrict__ x, const float* __restrict__ p,
                         float* __restrict__ scp){
  int s0 = blockIdx.x * 64;
  int b  = blockIdx.y;
  int kc = blockIdx.z;
  int kbase = kc * 256;
  int tid = threadIdx.x;
  __shared__ float4 plds[256*5];      // [d][h/4] transposed p chunk (20 KB)
  __shared__ float  xlds[64*68];      // [s][d] 64x64 tile, pad 68
  float* pf = (float*)plds;
  #pragma unroll
  for (int it=0; it<16; it++){        // stage p chunk: 256 d x 16 h
    int idx = it*256 + tid;
    int d = idx & 255, h = idx >> 8;
    pf[d*20 + h] = p[(size_t)(b*NH + h)*DIM + kbase + d];
  }
  int s = tid & 63, g = tid >> 6;     // wave-uniform g
  float acc[4] = {0.f,0.f,0.f,0.f};
  for (int dk=0; dk<4; dk++){
    __syncthreads();
    #pragma unroll
    for (int it=0; it<4; it++){       // stage x tile 64 s x 64 d via float4
      int idx = it*256 + tid;
      int dd4 = idx & 15, ss = idx >> 4;
      float4 v = *(const float4*)(x + (size_t)(b*SEQ + s0 + ss)*DIM + kbase + dk*64 + dd4*4);
      *(float4*)(xlds + ss*68 + dd4*4) = v;
    }
    __syncthreads();
    #pragma unroll 4
    for (int dd4=0; dd4<16; dd4++){
      float4 xq = *(const float4*)(xlds + s*68 + dd4*4);
      int dbase = (dk*64 + dd4*4)*5 + g;
      float4 p0 = plds[dbase], p1 = plds[dbase+5], p2 = plds[dbase+10], p3 = plds[dbase+15];
      acc[0] += xq.x*p0.x + xq.y*p1.x + xq.z*p2.x + xq.w*p3.x;
      acc[1] += xq.x*p0.y + xq.y*p1.y + xq.z*p2.y + xq.w*p3.y;
      acc[2] += xq.x*p0.z + xq.y*p1.z + xq.z*p2.z + xq.w*p3.z;
      acc[3] += xq.x*p0.w + xq.y*p1.w + xq.z*p2.w + xq.w*p3.w;
    }
  }
  float* slab = scp + (size_t)kc*(BS*NH*SEQ);
  #pragma unroll
  for (int u=0; u<4; u++)
    slab[(size_t)(b*NH + g*4 + u)*SEQ + s0 + s] = acc[u];
}

// ---------------- K3: fused exp + weighted pool (softmax-free) --------------
// e[s,h] = mask * exp(sum_kc scp); num partial = sum_s e*x; den partial = sum_s e.
// grid (4 dc, 8 b, 16 scn), block 256 = 4 waves; wave wv -> heads wv*4..+3.
__global__ void k_wpe(const float* __restrict__ x, const float* __restrict__ scp,
                      const int* __restrict__ mask,
                      float* __restrict__ nump, float* __restrict__ denp){
  int dc = blockIdx.x, b = blockIdx.y, scn = blockIdx.z;
  int tid = threadIdx.x;
  __shared__ float4 wlds[64*5];       // [s][h/4] e-values (5 KB)
  float* wf = (float*)wlds;
  #pragma unroll
  for (int it=0; it<4; it++){         // compute e for 64 s x 16 h
    int idx = it*256 + tid;
    int ss = idx >> 4, hh = idx & 15;
    int s  = scn*64 + ss;
    float sc = 0.f;
    #pragma unroll
    for (int kc=0; kc<4; kc++)
      sc += scp[(size_t)kc*(BS*NH*SEQ) + (size_t)(b*NH + hh)*SEQ + s];
    wf[ss*20 + hh] = mask[b*SEQ + s] ? __expf(sc) : 0.f;
  }
  __syncthreads();
  if (dc == 0 && tid < 16){           // den partial per head (once per (b,scn))
    float dsum = 0.f;
    #pragma unroll 16
    for (int ss=0; ss<64; ss++) dsum += wf[ss*20 + tid];
    denp[(scn*BS + b)*NH + tid] = dsum;
  }
  int ln = tid & 63, wv = tid >> 6;
  int d = dc*256 + ln*4;
  const float* xbase = x + (size_t)(b*SEQ + scn*64)*DIM + d;
  float4 a0={0,0,0,0}, a1={0,0,0,0}, a2={0,0,0,0}, a3={0,0,0,0};
  for (int sb=0; sb<64; sb+=8){
    float4 xq[8];
    #pragma unroll
    for (int u=0; u<8; u++)
      xq[u] = *(const float4*)(xbase + (size_t)(sb+u)*DIM);   // 8 loads in flight
    #pragma unroll
    for (int u=0; u<8; u++){
      float4 wq = wlds[(sb+u)*5 + wv];  // wave-uniform broadcast
      a0.x+=xq[u].x*wq.x; a0.y+=xq[u].y*wq.x; a0.z+=xq[u].z*wq.x; a0.w+=xq[u].w*wq.x;
      a1.x+=xq[u].x*wq.y; a1.y+=xq[u].y*wq.y; a1.z+=xq[u].z*wq.y; a1.w+=xq[u].w*wq.y;
      a2.x+=xq[u].x*wq.z; a2.y+=xq[u].y*wq.z; a2.z+=xq[u].z*wq.z; a2.w+=xq[u].w*wq.z;
      a3.x+=xq[u].x*wq.w; a3.y+=xq[u].y*wq.w; a3.z+=xq[u].z*wq.w; a3.w+=xq[u].w*wq.w;
    }
  }
  float* dst = nump + (size_t)scn*(BS*NH*DIM) + (size_t)(b*NH + wv*4)*DIM + d;
  *(float4*)(dst                 ) = a0;
  *(float4*)(dst +   (size_t)DIM ) = a1;
  *(float4*)(dst + 2*(size_t)DIM ) = a2;
  *(float4*)(dst + 3*(size_t)DIM ) = a3;
}

// ---------------- K4: xw[b,h,d] = sum_scn num / sum_scn den ----------------
__global__ void k_xwred(const float* __restrict__ nump, const float* __restrict__ denp,
                        float* __restrict__ xw){
  int id = blockIdx.x*256 + threadIdx.x;   // 512 blocks -> 131072 ids
  int bh = id >> 10;                        // b*NH + h
  int b = bh >> 4, h = bh & 15;
  float den = 0.f;
  #pragma unroll
  for (int scn=0; scn<16; scn++) den += denp[(scn*BS + b)*NH + h];
  float num = 0.f;
  #pragma unroll
  for (int scn=0; scn<16; scn++) num += nump[(size_t)scn*(BS*NH*DIM) + id];
  xw[id] = num / den;
}

// ---------------- K5: ctx[b,jo] = xw[b,h(jo),:].vw[jo,:] + vb[jo] ----------
__global__ void k_ctx(const float* __restrict__ xw, const float* __restrict__ vw,
                      const float* __restrict__ vb, float* __restrict__ ctx){
  int wv = threadIdx.x >> 6, ln = threadIdx.x & 63;
  int jo = blockIdx.x*4 + wv;
  int h  = jo >> 6;
  float acc[BS] = {0,0,0,0,0,0,0,0};
  #pragma unroll
  for (int i=0; i<4; i++){
    int d = ln*4 + 256*i;
    float4 vv = *(const float4*)(vw + (size_t)jo*DIM + d);
    #pragma unroll
    for (int b=0; b<BS; b++){
      float4 xv = *(const float4*)(xw + (size_t)(b*NH + h)*DIM + d);
      acc[b] += vv.x*xv.x + vv.y*xv.y + vv.z*xv.z + vv.w*xv.w;
    }
  }
  #pragma unroll
  for (int off=32; off>=1; off>>=1){
    #pragma unroll
    for (int b=0; b<BS; b++) acc[b] += __shfl_down(acc[b], off, 64);
  }
  if (ln == 0){
    float bias = vb[jo];
    #pragma unroll
    for (int b=0; b<BS; b++) ctx[b*DIM + jo] = acc[b] + bias;
  }
}

// ---------------- K6: out_row[b,i] = ctx[b,:].ow[i,:] + ob[i] ----------------
__global__ void k_outrow(const float* __restrict__ ctx, const float* __restrict__ ow,
                         const float* __restrict__ ob, float* __restrict__ outr){
  int wv = threadIdx.x >> 6, ln = threadIdx.x & 63;
  int io = blockIdx.x*4 + wv;
  float acc[BS] = {0,0,0,0,0,0,0,0};
  #pragma unroll
  for (int i=0; i<4; i++){
    int d = ln*4 + 256*i;
    float4 wt = *(const float4*)(ow + (size_t)io*DIM + d);
    #pragma unroll
    for (int b=0; b<BS; b++){
      float4 cv = *(const float4*)(ctx + b*DIM + d);
      acc[b] += wt.x*cv.x + wt.y*cv.y + wt.z*cv.z + wt.w*cv.w;
    }
  }
  #pragma unroll
  for (int off=32; off>=1; off>>=1){
    #pragma unroll
    for (int b=0; b<BS; b++) acc[b] += __shfl_down(acc[b], off, 64);
  }
  if (ln == 0){
    float bias = ob[io];
    #pragma unroll
    for (int b=0; b<BS; b++) outr[b*DIM + io] = acc[b] + bias;
  }
}

// ---------------- K7: out[b,s,:] = LN(out_row[b]+x[b,s,:])*g + beta ---------
__global__ void k_ln(const float* __restrict__ x, const float* __restrict__ outr,
                     const float* __restrict__ g, const float* __restrict__ bt,
                     float* __restrict__ out){
  int row = blockIdx.x;
  int b = row >> 10;
  size_t base = (size_t)row * DIM;
  int tid = threadIdx.x;
  float4 xv = ((const float4*)(x + base))[tid];
  float4 ov = ((const float4*)(outr + (size_t)b*DIM))[tid];
  float4 h;
  h.x = xv.x + ov.x; h.y = xv.y + ov.y; h.z = xv.z + ov.z; h.w = xv.w + ov.w;
  float s  = h.x + h.y + h.z + h.w;
  float s2 = h.x*h.x + h.y*h.y + h.z*h.z + h.w*h.w;
  #pragma unroll
  for (int off=32; off>=1; off>>=1){
    s  += __shfl_xor(s,  off, 64);
    s2 += __shfl_xor(s2, off, 64);
  }
  __shared__ float r1[4], r2[4];
  int wv = tid >> 6, ln = tid & 63;
  if (ln == 0){ r1[wv] = s; r2[wv] = s2; }
  __syncthreads();
  s  = r1[0] + r1[1] + r1[2] + r1[3];
  s2 = r2[0] + r2[1] + r2[2] + r2[3];
  float mu   = s  * (1.f/1024.f);
  float var  = s2 * (1.f/1024.f) - mu*mu;
  float rstd = rsqrtf(var + 1e-12f);
  float4 gv = ((const float4*)g)[tid];
  float4 bv = ((const float4*)bt)[tid];
  float4 y;
  y.x = (h.x - mu)*rstd*gv.x + bv.x;
  y.y = (h.y - mu)*rstd*gv.y + bv.y;
  y.z = (h.z - mu)*rstd*gv.z + bv.z;
  y.w = (h.w - mu)*rstd*gv.w + bv.w;
  ((float4*)(out + base))[tid] = y;
}

extern "C" void kernel_launch(void* const* d_in, const int* in_sizes, int n_in,
                              void* d_out, int out_size, void* d_ws, size_t ws_size,
                              hipStream_t stream) {
  const float* x    = (const float*)d_in[0];
  const float* xnb  = (const float*)d_in[1];
  const int*   mask = (const int*  )d_in[2];
  const float* nm   = (const float*)d_in[3];
  const float* qw   = (const float*)d_in[4];
  const float* qb   = (const float*)d_in[5];
  const float* kw   = (const float*)d_in[6];
  // d_in[7] = kb: softmax-invariant constant, unused
  const float* vw   = (const float*)d_in[8];
  const float* vb   = (const float*)d_in[9];
  const float* ow   = (const float*)d_in[10];
  const float* ob   = (const float*)d_in[11];
  const float* lng  = (const float*)d_in[12];
  const float* lnb  = (const float*)d_in[13];
  float* out = (float*)d_out;

  float* ws   = (float*)d_ws;              // ~11.6 MB of ~256 MB ws
  float* p    = ws + OF_P;
  float* scp  = ws + OF_SCP;               // 4 kc-slabs
  float* nump = ws + OF_NUMP;              // 16 s-chunk slabs
  float* denp = ws + OF_DENP;              // 16 x 128
  float* xw   = ws + OF_XW;
  float* ctx  = ws + OF_CTX;
  float* outr = ws + OF_OUTR;

  k_prep  <<<128,             256, 0, stream>>>(xnb, nm, qw, qb, kw, p);
  k_scores<<<dim3(16,BS,4),   256, 0, stream>>>(x, p, scp);
  k_wpe   <<<dim3(4,BS,16),   256, 0, stream>>>(x, scp, mask, nump, denp);
  k_xwred <<<512,             256, 0, stream>>>(nump, denp, xw);
  k_ctx   <<<256,             256, 0, stream>>>(xw, vw, vb, ctx);
  k_outrow<<<256,             256, 0, stream>>>(ctx, ow, ob, outr);
  k_ln    <<<BS*SEQ,          256, 0, stream>>>(x, outr, lng, lnb, out);
}